// Round 4
// baseline (395.758 us; speedup 1.0000x reference)
//
#include <hip/hip_runtime.h>
#include <stdint.h>

#define DIM 128
#define RNB 32
#define EFS 64
#define KTOP 10
#define INFD 1e30f
#define NSET 512

typedef unsigned long long u64;

__device__ __forceinline__ u64 shflx64(u64 v, int m) {
    return (u64)__shfl_xor((long long)v, m, 64);
}
__device__ __forceinline__ u64 shfl64(u64 v, int src) {
    return (u64)__shfl((long long)v, src, 64);
}
__device__ __forceinline__ u64 dsperm64(int dst_byte, u64 v) {
    int lo = __builtin_amdgcn_ds_permute(dst_byte, (int)(unsigned)(v & 0xffffffffu));
    int hi = __builtin_amdgcn_ds_permute(dst_byte, (int)(unsigned)(v >> 32));
    return ((u64)(unsigned)hi << 32) | (unsigned)lo;
}
__device__ __forceinline__ u64 readlane64(u64 v, int l) {
    unsigned lo = (unsigned)__builtin_amdgcn_readlane((int)(unsigned)(v & 0xffffffffu), l);
    unsigned hi = (unsigned)__builtin_amdgcn_readlane((int)(unsigned)(v >> 32), l);
    return ((u64)hi << 32) | lo;
}
__device__ __forceinline__ int hset(int id) {
    return (id ^ (id >> 9)) & (NSET - 1);
}

// ---------------- exact slow-path merge (validated rounds 1-3) ----------------
__device__ __forceinline__ void bitonic128(u64 &e0, u64 &e1, int lane) {
    #pragma unroll
    for (int k = 2; k <= 128; k <<= 1) {
        #pragma unroll
        for (int j = k >> 1; j >= 1; j >>= 1) {
            if (j == 64) {
                u64 lo = e0 < e1 ? e0 : e1;
                u64 hi = e0 < e1 ? e1 : e0;
                e0 = lo; e1 = hi;
            } else {
                u64 o0 = shflx64(e0, j);
                u64 o1 = shflx64(e1, j);
                int i0 = lane, i1 = lane + 64;
                bool keepmin0 = ((i0 & k) == 0) == ((i0 & j) == 0);
                bool keepmin1 = ((i1 & k) == 0) == ((i1 & j) == 0);
                e0 = keepmin0 ? (e0 < o0 ? e0 : o0) : (e0 > o0 ? e0 : o0);
                e1 = keepmin1 ? (e1 < o1 ? e1 : o1) : (e1 > o1 ? e1 : o1);
            }
        }
    }
}

__device__ __forceinline__ void merge_slow(int n, int lane,
                                           int* ids_s, float* dst_s, int* exp_s,
                                           int* ids2, float* dst2, int* exp2) {
    __syncthreads();
    {
        int i1 = lane + 64;
        u64 e0 = ((u64)(uint32_t)(ids_s[lane] * 2 + (exp_s[lane] ? 0 : 1)) << 32) | (uint32_t)lane;
        u64 e1 = ~0ULL;
        if (i1 < n)
            e1 = ((u64)(uint32_t)(ids_s[i1] * 2 + (exp_s[i1] ? 0 : 1)) << 32) | (uint32_t)i1;
        bitonic128(e0, e1, lane);

        int id0 = -1, id1 = -1; float d0 = INFD, d1 = INFD; int x0 = 1, x1 = 1;
        { int p = (int)(e0 & 0xffffffffu); id0 = ids_s[p]; d0 = dst_s[p]; x0 = exp_s[p]; }
        if (e1 != ~0ULL) { int p = (int)(e1 & 0xffffffffu); id1 = ids_s[p]; d1 = dst_s[p]; x1 = exp_s[p]; }

        int prev0 = __shfl_up(id0, 1);
        int top0  = __shfl(id0, 63);
        int prev1 = __shfl_up(id1, 1);
        bool dup0 = (lane > 0) && (id0 == prev0);
        bool dup1 = (i1 < n) && (id1 == ((lane == 0) ? top0 : prev1));
        if (dup0) { d0 = INFD; x0 = 1; }
        if (dup1) { d1 = INFD; x1 = 1; }

        ids2[lane] = id0; dst2[lane] = d0; exp2[lane] = x0;
        ids2[i1]   = id1; dst2[i1]   = d1; exp2[i1]   = x1;

        u64 f0 = ((u64)__float_as_uint(d0) << 32) | (uint32_t)lane;
        u64 f1 = (i1 < n) ? (((u64)__float_as_uint(d1) << 32) | (uint32_t)i1) : ~0ULL;
        bitonic128(f0, f1, lane);

        int pf = (int)(f0 & 0xffffffffu);
        int idf = ids2[pf]; float df = dst2[pf]; int xf = exp2[pf];
        __syncthreads();
        ids_s[lane] = idf; dst_s[lane] = df; exp_s[lane] = xf;
    }
    __syncthreads();
}

// probe LDS neighbor cache for `NODE` (uniform), fall back to global;
// then issue next step's storage-row loads and indices-row prefetch.
#define PROBE_AND_PREFETCH(NODE) do {                                          \
    int set_n_ = hset(NODE);                                                   \
    int tg_ = tag_s[set_n_];                                                   \
    if (tg_ == (NODE)) nid = row_s[set_n_][lane & 31];                         \
    else               nid = indices[(size_t)(NODE) * RNB + (lane & 31)];      \
    _Pragma("unroll")                                                          \
    for (int p_ = 0; p_ < 4; ++p_) {                                           \
        int g_ = p_ * 8 + (lane >> 3);                                         \
        int idp_ = __shfl(nid, g_);                                            \
        const float4* row_ = (const float4*)(storage + (size_t)idp_ * DIM) + (lane & 7) * 4; \
        va[p_][0] = row_[0]; va[p_][1] = row_[1];                              \
        va[p_][2] = row_[2]; va[p_][3] = row_[3];                              \
    }                                                                          \
    if (lane < RNB) {                                                          \
        const int4* ip_ = (const int4*)(indices + (size_t)nid * RNB);          \
        _Pragma("unroll")                                                      \
        for (int c_ = 0; c_ < 8; ++c_) ir[c_] = ip_[c_];                       \
    }                                                                          \
} while (0)

// post-merge carried state: kill mask for the new candidates, insert-prune
// mask, and beam-key summaries. All off the critical path.
#define POSTMERGE_STATE() do {                                                 \
    killmask = 0u;                                                             \
    _Pragma("unroll")                                                          \
    for (int j_ = 0; j_ < RNB; ++j_) {                                         \
        int idj_ = __builtin_amdgcn_readlane(nid, j_);                         \
        u64 beq_ = __ballot(bid == idj_);                                      \
        u64 neq_ = __ballot(nid == idj_);                                      \
        u64 kj_ = beq_ | (neq_ & ((1ull << j_) - 1ull));                       \
        killmask |= (kj_ ? 1u : 0u) << j_;                                     \
    }                                                                          \
    setl = hset(nid);                                                          \
    lose = false;                                                              \
    _Pragma("unroll")                                                          \
    for (int j_ = 0; j_ < RNB; ++j_) {                                         \
        int sj_ = __builtin_amdgcn_readlane(setl, j_);                         \
        lose = lose || ((setl == sj_) && ((lane & 31) < j_));                  \
    }                                                                          \
    u64 bkeyN_ = ((u64)__float_as_uint(bds) << 27)                             \
               | ((u64)(unsigned)(bid * 2 + (bex ? 0 : 1)) << 7)               \
               | (unsigned)lane;                                               \
    bkey63 = readlane64(bkeyN_, 63);                                           \
    u64 bo_ = __ballot(bex == 0);                                              \
    K_bopen = bo_ ? readlane64(bkeyN_, (int)(__ffsll((long long)bo_) - 1)) : ~0ull; \
} while (0)

// ---------------------------------------------------------------------------
extern "C" __global__ __launch_bounds__(64, 1)
void nsw_search(const float* __restrict__ query,
                const float* __restrict__ storage,
                const int* __restrict__ indices,
                const int* __restrict__ entry,
                float* __restrict__ out,
                int B) {
    const int b = blockIdx.x;
    const int lane = threadIdx.x;  // 0..63, single wave

    __shared__ __align__(16) float q_s[DIM];
    __shared__ int tag_s[NSET];
    __shared__ __align__(16) int row_s[NSET][RNB];
    __shared__ int   ids_s[96];
    __shared__ float dst_s[96];
    __shared__ int   exp_s[96];
    __shared__ int   ids2[128];
    __shared__ float dst2[128];
    __shared__ int   exp2[128];

    // init cache tags
    #pragma unroll
    for (int c = 0; c < NSET / 64; ++c) tag_s[c * 64 + lane] = -1;

    q_s[lane]      = query[(size_t)b * DIM + lane];
    q_s[64 + lane] = query[(size_t)b * DIM + 64 + lane];
    ids_s[lane] = entry[(size_t)b * EFS + lane];
    exp_s[lane] = 0;
    __syncthreads();

    // ---- initial distances (exact round-1 arithmetic, loads batched 2 passes)
    {
        float4 ea[16];
        #pragma unroll
        for (int batch = 0; batch < 2; ++batch) {
            #pragma unroll
            for (int pp = 0; pp < 2; ++pp) {
                int p = batch * 2 + pp, g = p * 16 + (lane >> 2), sub = lane & 3;
                int id = ids_s[g];
                const float4* row = (const float4*)(storage + (size_t)id * DIM);
                #pragma unroll
                for (int c = 0; c < 8; ++c) ea[pp * 8 + c] = row[sub * 8 + c];
            }
            #pragma unroll
            for (int pp = 0; pp < 2; ++pp) {
                int p = batch * 2 + pp, g = p * 16 + (lane >> 2), sub = lane & 3;
                const float4* q4 = (const float4*)q_s;
                float acc = 0.f;
                #pragma unroll
                for (int c = 0; c < 8; ++c) {
                    float4 v = ea[pp * 8 + c];
                    float4 qv = q4[sub * 8 + c];
                    float dx = v.x - qv.x; acc = fmaf(dx, dx, acc);
                    dx = v.y - qv.y; acc = fmaf(dx, dx, acc);
                    dx = v.z - qv.z; acc = fmaf(dx, dx, acc);
                    dx = v.w - qv.w; acc = fmaf(dx, dx, acc);
                }
                acc += __shfl_xor(acc, 1);
                acc += __shfl_xor(acc, 2);
                if (sub == 0) dst_s[g] = acc;
            }
        }
    }

    merge_slow(64, lane, ids_s, dst_s, exp_s, ids2, dst2, exp2);

    int   bid = ids_s[lane];
    float bds = dst_s[lane];
    int   bex = exp_s[lane];

    // q chunk for step distances (sub = lane&7 -> dims [sub*16, sub*16+16))
    float4 qv0, qv1, qv2, qv3;
    {
        const float4* q4 = (const float4*)q_s;
        int sub = lane & 7;
        qv0 = q4[sub * 4 + 0]; qv1 = q4[sub * 4 + 1];
        qv2 = q4[sub * 4 + 2]; qv3 = q4[sub * 4 + 3];
    }

    // carried state
    int nid;                    // current candidates' ids (lane&31, mirrored)
    float4 va[4][4];            // candidates' storage rows
    int4 ir[8];                 // candidates' indices rows (lanes<32)
    unsigned killmask = 0;      // dedup kills for current candidates
    int  setl = 0;              // cache set per candidate
    bool lose = false;          // insert prune flag
    u64  K_bopen, bkey63;

    // ---- prologue select (#1) + first loads
    {
        u64 open = __ballot(bex == 0);
        int sel = open ? (int)(__ffsll((long long)open) - 1) : 0;
        int node = __shfl(bid, sel);
        if (lane == sel) bex = 1;
        PROBE_AND_PREFETCH(node);   // cold cache -> global path
        POSTMERGE_STATE();
    }

    for (int step = 0; step < EFS; ++step) {
        const bool lastit = (step + 1 == EFS);

        // ---- distances from preloaded registers (exact round-2/3 arithmetic)
        float accs[4];
        #pragma unroll
        for (int p = 0; p < 4; ++p) {
            float acc = 0.f;
            float4 v;
            v = va[p][0];
            { float dx = v.x - qv0.x; acc = fmaf(dx, dx, acc);
              dx = v.y - qv0.y; acc = fmaf(dx, dx, acc);
              dx = v.z - qv0.z; acc = fmaf(dx, dx, acc);
              dx = v.w - qv0.w; acc = fmaf(dx, dx, acc); }
            v = va[p][1];
            { float dx = v.x - qv1.x; acc = fmaf(dx, dx, acc);
              dx = v.y - qv1.y; acc = fmaf(dx, dx, acc);
              dx = v.z - qv1.z; acc = fmaf(dx, dx, acc);
              dx = v.w - qv1.w; acc = fmaf(dx, dx, acc); }
            v = va[p][2];
            { float dx = v.x - qv2.x; acc = fmaf(dx, dx, acc);
              dx = v.y - qv2.y; acc = fmaf(dx, dx, acc);
              dx = v.z - qv2.z; acc = fmaf(dx, dx, acc);
              dx = v.w - qv2.w; acc = fmaf(dx, dx, acc); }
            v = va[p][3];
            { float dx = v.x - qv3.x; acc = fmaf(dx, dx, acc);
              dx = v.y - qv3.y; acc = fmaf(dx, dx, acc);
              dx = v.z - qv3.z; acc = fmaf(dx, dx, acc);
              dx = v.w - qv3.w; acc = fmaf(dx, dx, acc); }
            acc += __shfl_xor(acc, 1);
            acc += __shfl_xor(acc, 2);
            acc += __shfl_xor(acc, 4);
            accs[p] = acc;
        }
        int l8 = (lane & 7) << 3;
        float t0 = __shfl(accs[0], l8), t1 = __shfl(accs[1], l8);
        float t2 = __shfl(accs[2], l8), t3 = __shfl(accs[3], l8);
        int ps = (lane >> 3) & 3;
        float ndt = (ps & 2) ? ((ps & 1) ? t3 : t2) : ((ps & 1) ? t1 : t0);

        // ---- insert current candidates' indices rows into the LDS cache
        // (ir/setl/lose computed last step; prune guarantees single writer)
        if (lane < RNB && !lose) {
            tag_s[setl] = nid;
            #pragma unroll
            for (int c = 0; c < 8; ++c) *(int4*)&row_s[setl][c * 4] = ir[c];
        }

        bool has_inf = (__ballot(bds >= INFD) != 0ull);

        if (!has_inf) {
            // ---- fast path ------------------------------------------------
            bool kill = (killmask >> (lane & 31)) & 1u;
            float dk = kill ? INFD : ndt;
            u64 nkey = ((u64)__float_as_uint(dk) << 27)
                     | ((u64)(unsigned)(nid * 2 + 1) << 7)
                     | (unsigned)(64 + (lane & 31));

            int rank = 0;
            #pragma unroll
            for (int j = 0; j < RNB; ++j) {
                u64 kj = readlane64(nkey, j);
                rank += (kj < nkey) ? 1 : 0;
            }
            u64 rz = __ballot(rank == 0) & 0xffffffffull;
            u64 K_newmin = readlane64(nkey, (int)(__ffsll((long long)rz) - 1));
            u64 K_minopen = (K_bopen < K_newmin) ? K_bopen : K_newmin;
            bool fallback = (K_minopen > bkey63);
            int node = fallback ? __builtin_amdgcn_readlane(bid, 0)
                                : (int)(((unsigned)((K_minopen >> 7) & 0xFFFFFu)) >> 1);

            u64 bkey = ((u64)__float_as_uint(bds) << 27)
                     | ((u64)(unsigned)(bid * 2 + (bex ? 0 : 1)) << 7)
                     | (unsigned)lane;

            // critical path: probe cache + issue next loads ASAP
            if (!lastit) PROBE_AND_PREFETCH(node);

            // merge (off critical path, hidden under the storage loads)
            u64 e1p = dsperm64((lane < 32) ? ((63 - rank) << 2) : 0, nkey);
            u64 e0 = bkey;
            u64 e1 = (lane < 32) ? ~0ull : e1p;
            { u64 lo = e0 < e1 ? e0 : e1; e0 = lo; }
            #pragma unroll
            for (int j = 32; j >= 1; j >>= 1) {
                u64 o0 = shflx64(e0, j);
                bool keepmin = (lane & j) == 0;
                e0 = keepmin ? (e0 < o0 ? e0 : o0) : (e0 > o0 ? e0 : o0);
            }
            bds = __uint_as_float((unsigned)(e0 >> 27));
            unsigned key1 = (unsigned)((e0 >> 7) & 0xFFFFFu);
            bid = (int)(key1 >> 1);
            bex = (int)((key1 & 1u) ^ 1u);
            if (!fallback && e0 == K_minopen) bex = 1;
        } else {
            // ---- exact slow path (INF tombstones present; rare) ------------
            ids_s[lane] = bid; dst_s[lane] = bds; exp_s[lane] = bex;
            if (lane < RNB) { ids_s[64 + lane] = nid; dst_s[64 + lane] = ndt; exp_s[64 + lane] = 0; }
            merge_slow(96, lane, ids_s, dst_s, exp_s, ids2, dst2, exp2);
            bid = ids_s[lane]; bds = dst_s[lane]; bex = exp_s[lane];
            u64 open = __ballot(bex == 0);
            int sel = open ? (int)(__ffsll((long long)open) - 1) : 0;
            int node = __shfl(bid, sel);
            if (lane == sel) bex = 1;
            if (!lastit) PROBE_AND_PREFETCH(node);
        }

        if (!lastit) POSTMERGE_STATE();
    }

    // ---- outputs: ids (as float, exact for id < 2^24) then dists
    if (lane < KTOP) {
        out[(size_t)b * KTOP + lane] = (float)bid;
        out[(size_t)B * KTOP + (size_t)b * KTOP + lane] = bds;
    }
}

extern "C" void kernel_launch(void* const* d_in, const int* in_sizes, int n_in,
                              void* d_out, int out_size, void* d_ws, size_t ws_size,
                              hipStream_t stream) {
    const float* query   = (const float*)d_in[0];
    const float* storage = (const float*)d_in[1];
    const int*   indices = (const int*)d_in[2];
    const int*   entry   = (const int*)d_in[3];
    int B = in_sizes[0] / DIM;
    float* out = (float*)d_out;
    nsw_search<<<B, 64, 0, stream>>>(query, storage, indices, entry, out, B);
}

// Round 5
// 193.112 us; speedup vs baseline: 2.0494x; 2.0494x over previous
//
#include <hip/hip_runtime.h>
#include <stdint.h>

#define DIM 128
#define RNB 32
#define EFS 64
#define KTOP 10
#define INFD 1e30f

typedef unsigned long long u64;

__device__ __forceinline__ u64 shflx64(u64 v, int m) {
    return (u64)__shfl_xor((long long)v, m, 64);
}
__device__ __forceinline__ u64 dsperm64(int dst_byte, u64 v) {
    int lo = __builtin_amdgcn_ds_permute(dst_byte, (int)(unsigned)(v & 0xffffffffu));
    int hi = __builtin_amdgcn_ds_permute(dst_byte, (int)(unsigned)(v >> 32));
    return ((u64)(unsigned)hi << 32) | (unsigned)lo;
}
__device__ __forceinline__ u64 readlane64(u64 v, int l) {
    unsigned lo = (unsigned)__builtin_amdgcn_readlane((int)(unsigned)(v & 0xffffffffu), l);
    unsigned hi = (unsigned)__builtin_amdgcn_readlane((int)(unsigned)(v >> 32), l);
    return ((u64)hi << 32) | lo;
}
// x + (value of x at DPP-mapped lane). Bit-exact replacement for
// acc += __shfl_xor(acc, m) at the lanes we consume (sub==0).
template <int CTRL>
__device__ __forceinline__ float dpp_add(float x) {
    int y = __builtin_amdgcn_mov_dpp(__float_as_int(x), CTRL, 0xF, 0xF, true);
    return x + __int_as_float(y);
}

// ---------------- exact slow-path merge (validated rounds 1-4) ----------------
__device__ __forceinline__ void bitonic128(u64 &e0, u64 &e1, int lane) {
    #pragma unroll
    for (int k = 2; k <= 128; k <<= 1) {
        #pragma unroll
        for (int j = k >> 1; j >= 1; j >>= 1) {
            if (j == 64) {
                u64 lo = e0 < e1 ? e0 : e1;
                u64 hi = e0 < e1 ? e1 : e0;
                e0 = lo; e1 = hi;
            } else {
                u64 o0 = shflx64(e0, j);
                u64 o1 = shflx64(e1, j);
                int i0 = lane, i1 = lane + 64;
                bool keepmin0 = ((i0 & k) == 0) == ((i0 & j) == 0);
                bool keepmin1 = ((i1 & k) == 0) == ((i1 & j) == 0);
                e0 = keepmin0 ? (e0 < o0 ? e0 : o0) : (e0 > o0 ? e0 : o0);
                e1 = keepmin1 ? (e1 < o1 ? e1 : o1) : (e1 > o1 ? e1 : o1);
            }
        }
    }
}

__device__ __forceinline__ void merge_slow(int n, int lane,
                                           int* ids_s, float* dst_s, int* exp_s,
                                           int* ids2, float* dst2, int* exp2) {
    __syncthreads();
    {
        int i1 = lane + 64;
        u64 e0 = ((u64)(uint32_t)(ids_s[lane] * 2 + (exp_s[lane] ? 0 : 1)) << 32) | (uint32_t)lane;
        u64 e1 = ~0ULL;
        if (i1 < n)
            e1 = ((u64)(uint32_t)(ids_s[i1] * 2 + (exp_s[i1] ? 0 : 1)) << 32) | (uint32_t)i1;
        bitonic128(e0, e1, lane);

        int id0 = -1, id1 = -1; float d0 = INFD, d1 = INFD; int x0 = 1, x1 = 1;
        { int p = (int)(e0 & 0xffffffffu); id0 = ids_s[p]; d0 = dst_s[p]; x0 = exp_s[p]; }
        if (e1 != ~0ULL) { int p = (int)(e1 & 0xffffffffu); id1 = ids_s[p]; d1 = dst_s[p]; x1 = exp_s[p]; }

        int prev0 = __shfl_up(id0, 1);
        int top0  = __shfl(id0, 63);
        int prev1 = __shfl_up(id1, 1);
        bool dup0 = (lane > 0) && (id0 == prev0);
        bool dup1 = (i1 < n) && (id1 == ((lane == 0) ? top0 : prev1));
        if (dup0) { d0 = INFD; x0 = 1; }
        if (dup1) { d1 = INFD; x1 = 1; }

        ids2[lane] = id0; dst2[lane] = d0; exp2[lane] = x0;
        ids2[i1]   = id1; dst2[i1]   = d1; exp2[i1]   = x1;

        u64 f0 = ((u64)__float_as_uint(d0) << 32) | (uint32_t)lane;
        u64 f1 = (i1 < n) ? (((u64)__float_as_uint(d1) << 32) | (uint32_t)i1) : ~0ULL;
        bitonic128(f0, f1, lane);

        int pf = (int)(f0 & 0xffffffffu);
        int idf = ids2[pf]; float df = dst2[pf]; int xf = exp2[pf];
        __syncthreads();
        ids_s[lane] = idf; dst_s[lane] = df; exp_s[lane] = xf;
    }
    __syncthreads();
}

// issue the neighbor-index loads for `NODE` (uniform): the per-lane candidate
// id, plus the 4 row ids this lane will address in LOAD_ROWS (same 128B line).
#define LOAD_IDX(NODE) do {                                                    \
    size_t ib_ = (size_t)(NODE) * RNB;                                         \
    nid = indices[ib_ + (lane & 31)];                                          \
    int g0_ = lane >> 3;                                                       \
    ida = indices[ib_ + g0_];                                                  \
    idb = indices[ib_ + 8 + g0_];                                              \
    idc = indices[ib_ + 16 + g0_];                                             \
    idd = indices[ib_ + 24 + g0_];                                             \
} while (0)

// issue the 16 storage float4 loads (addresses straight from ida..idd)
#define LOAD_ROWS() do {                                                       \
    const float4* r0_ = (const float4*)(storage + (size_t)ida * DIM) + (lane & 7) * 4; \
    va[0][0] = r0_[0]; va[0][1] = r0_[1]; va[0][2] = r0_[2]; va[0][3] = r0_[3]; \
    const float4* r1_ = (const float4*)(storage + (size_t)idb * DIM) + (lane & 7) * 4; \
    va[1][0] = r1_[0]; va[1][1] = r1_[1]; va[1][2] = r1_[2]; va[1][3] = r1_[3]; \
    const float4* r2_ = (const float4*)(storage + (size_t)idc * DIM) + (lane & 7) * 4; \
    va[2][0] = r2_[0]; va[2][1] = r2_[1]; va[2][2] = r2_[2]; va[2][3] = r2_[3]; \
    const float4* r3_ = (const float4*)(storage + (size_t)idd * DIM) + (lane & 7) * 4; \
    va[3][0] = r3_[0]; va[3][1] = r3_[1]; va[3][2] = r3_[2]; va[3][3] = r3_[3]; \
} while (0)

// off-chain state for the NEXT step (runs while storage loads are in flight):
// dedup kill mask, carried beam keys, open-min key, slow-path flag.
#define POSTMERGE_STATE() do {                                                 \
    killmask = 0u;                                                             \
    _Pragma("unroll")                                                          \
    for (int j_ = 0; j_ < RNB; ++j_) {                                         \
        int idj_ = __builtin_amdgcn_readlane(nid, j_);                         \
        u64 beq_ = __ballot(bid == idj_);                                      \
        u64 neq_ = __ballot(nid == idj_);                                      \
        u64 kj_ = beq_ | (neq_ & ((1ull << j_) - 1ull));                       \
        killmask |= (kj_ ? 1u : 0u) << j_;                                     \
    }                                                                          \
    bkey = ((u64)__float_as_uint(bds) << 27)                                   \
         | ((u64)(unsigned)(bid * 2 + (bex ? 0 : 1)) << 7)                     \
         | (unsigned)lane;                                                     \
    bkey63 = readlane64(bkey, 63);                                             \
    u64 bo_ = __ballot(bex == 0);                                              \
    K_bopen = bo_ ? readlane64(bkey, (int)(__ffsll((long long)bo_) - 1)) : ~0ull; \
    use_slow = (__ballot(bds >= INFD) != 0ull);                                \
} while (0)

// ---------------------------------------------------------------------------
extern "C" __global__ __launch_bounds__(64, 1)
void nsw_search(const float* __restrict__ query,
                const float* __restrict__ storage,
                const int* __restrict__ indices,
                const int* __restrict__ entry,
                float* __restrict__ out,
                int B) {
    const int b = blockIdx.x;
    const int lane = threadIdx.x;  // 0..63, single wave

    __shared__ __align__(16) float q_s[DIM];
    __shared__ int   ids_s[96];
    __shared__ float dst_s[96];
    __shared__ int   exp_s[96];
    __shared__ int   ids2[128];
    __shared__ float dst2[128];
    __shared__ int   exp2[128];

    q_s[lane]      = query[(size_t)b * DIM + lane];
    q_s[64 + lane] = query[(size_t)b * DIM + 64 + lane];
    ids_s[lane] = entry[(size_t)b * EFS + lane];
    exp_s[lane] = 0;
    __syncthreads();

    // ---- initial distances (exact round-1 arithmetic, validated)
    {
        float4 ea[16];
        #pragma unroll
        for (int batch = 0; batch < 2; ++batch) {
            #pragma unroll
            for (int pp = 0; pp < 2; ++pp) {
                int p = batch * 2 + pp, g = p * 16 + (lane >> 2), sub = lane & 3;
                int id = ids_s[g];
                const float4* row = (const float4*)(storage + (size_t)id * DIM);
                #pragma unroll
                for (int c = 0; c < 8; ++c) ea[pp * 8 + c] = row[sub * 8 + c];
            }
            #pragma unroll
            for (int pp = 0; pp < 2; ++pp) {
                int p = batch * 2 + pp, g = p * 16 + (lane >> 2), sub = lane & 3;
                const float4* q4 = (const float4*)q_s;
                float acc = 0.f;
                #pragma unroll
                for (int c = 0; c < 8; ++c) {
                    float4 v = ea[pp * 8 + c];
                    float4 qv = q4[sub * 8 + c];
                    float dx = v.x - qv.x; acc = fmaf(dx, dx, acc);
                    dx = v.y - qv.y; acc = fmaf(dx, dx, acc);
                    dx = v.z - qv.z; acc = fmaf(dx, dx, acc);
                    dx = v.w - qv.w; acc = fmaf(dx, dx, acc);
                }
                acc += __shfl_xor(acc, 1);
                acc += __shfl_xor(acc, 2);
                if (sub == 0) dst_s[g] = acc;
            }
        }
    }

    merge_slow(64, lane, ids_s, dst_s, exp_s, ids2, dst2, exp2);

    int   bid = ids_s[lane];
    float bds = dst_s[lane];
    int   bex = exp_s[lane];

    // q chunk for step distances (sub = lane&7 -> dims [sub*16, sub*16+16))
    float4 qv0, qv1, qv2, qv3;
    {
        const float4* q4 = (const float4*)q_s;
        int sub = lane & 7;
        qv0 = q4[sub * 4 + 0]; qv1 = q4[sub * 4 + 1];
        qv2 = q4[sub * 4 + 2]; qv3 = q4[sub * 4 + 3];
    }

    // carried state
    int nid, ida, idb, idc, idd;
    float4 va[4][4];
    unsigned killmask = 0;
    u64 K_bopen = ~0ull, bkey63 = ~0ull, bkey = 0;
    bool use_slow = false;

    // ---- prologue: select #1, issue loads, precompute off-chain state
    {
        u64 open = __ballot(bex == 0);
        int sel = open ? (int)(__ffsll((long long)open) - 1) : 0;
        int node = __shfl(bid, sel);
        if (lane == sel) bex = 1;
        LOAD_IDX(node);
        LOAD_ROWS();
        POSTMERGE_STATE();
    }

    for (int step = 0; step < EFS; ++step) {
        const bool lastit = (step + 1 == EFS);

        // ---- distances from preloaded registers (bit-exact vs R3 at the
        // consumed sub==0 lanes; DPP replaces the xor-shuffle tree)
        float accs[4];
        #pragma unroll
        for (int p = 0; p < 4; ++p) {
            float acc = 0.f;
            float4 v;
            v = va[p][0];
            { float dx = v.x - qv0.x; acc = fmaf(dx, dx, acc);
              dx = v.y - qv0.y; acc = fmaf(dx, dx, acc);
              dx = v.z - qv0.z; acc = fmaf(dx, dx, acc);
              dx = v.w - qv0.w; acc = fmaf(dx, dx, acc); }
            v = va[p][1];
            { float dx = v.x - qv1.x; acc = fmaf(dx, dx, acc);
              dx = v.y - qv1.y; acc = fmaf(dx, dx, acc);
              dx = v.z - qv1.z; acc = fmaf(dx, dx, acc);
              dx = v.w - qv1.w; acc = fmaf(dx, dx, acc); }
            v = va[p][2];
            { float dx = v.x - qv2.x; acc = fmaf(dx, dx, acc);
              dx = v.y - qv2.y; acc = fmaf(dx, dx, acc);
              dx = v.z - qv2.z; acc = fmaf(dx, dx, acc);
              dx = v.w - qv2.w; acc = fmaf(dx, dx, acc); }
            v = va[p][3];
            { float dx = v.x - qv3.x; acc = fmaf(dx, dx, acc);
              dx = v.y - qv3.y; acc = fmaf(dx, dx, acc);
              dx = v.z - qv3.z; acc = fmaf(dx, dx, acc);
              dx = v.w - qv3.w; acc = fmaf(dx, dx, acc); }
            acc = dpp_add<0xB1>(acc);   // += partner xor 1 (quad_perm)
            acc = dpp_add<0x4E>(acc);   // += partner xor 2 (quad_perm)
            acc = dpp_add<0x104>(acc);  // += lane+4 (row_shl:4), valid at sub==0
            accs[p] = acc;
        }
        int l8 = (lane & 7) << 3;
        float t0 = __shfl(accs[0], l8), t1 = __shfl(accs[1], l8);
        float t2 = __shfl(accs[2], l8), t3 = __shfl(accs[3], l8);
        int ps = (lane >> 3) & 3;
        float ndt = (ps & 2) ? ((ps & 1) ? t3 : t2) : ((ps & 1) ? t1 : t0);

        if (!use_slow) {
            // ---- fast path ------------------------------------------------
            bool kill = (killmask >> (lane & 31)) & 1u;
            float dk = kill ? INFD : ndt;
            u64 nkey = ((u64)__float_as_uint(dk) << 27)
                     | ((u64)(unsigned)(nid * 2 + 1) << 7)
                     | (unsigned)(64 + (lane & 31));

            // fused min+rank scan over the 32 new keys (VALU readlanes)
            u64 kmin = ~0ull; int rank = 0;
            #pragma unroll
            for (int j = 0; j < RNB; ++j) {
                u64 kj = readlane64(nkey, j);
                kmin = (kj < kmin) ? kj : kmin;
                rank += (kj < nkey) ? 1 : 0;
            }
            u64 K_minopen = (K_bopen < kmin) ? K_bopen : kmin;
            bool fallback = (K_minopen > bkey63);
            int node = fallback ? __builtin_amdgcn_readlane(bid, 0)
                                : (int)(((unsigned)((K_minopen >> 7) & 0xFFFFFu)) >> 1);

            // critical path: issue next neighbor-index loads ASAP
            if (!lastit) LOAD_IDX(node);

            // merge (hides the indices load)
            u64 e1p = dsperm64((lane < 32) ? ((63 - rank) << 2) : 0, nkey);
            u64 e0 = bkey;
            u64 e1 = (lane < 32) ? ~0ull : e1p;
            { u64 lo = e0 < e1 ? e0 : e1; e0 = lo; }
            #pragma unroll
            for (int j = 32; j >= 1; j >>= 1) {
                u64 o0 = shflx64(e0, j);
                bool keepmin = (lane & j) == 0;
                e0 = keepmin ? (e0 < o0 ? e0 : o0) : (e0 > o0 ? e0 : o0);
            }
            bds = __uint_as_float((unsigned)(e0 >> 27));
            unsigned key1 = (unsigned)((e0 >> 7) & 0xFFFFFu);
            bid = (int)(key1 >> 1);
            bex = (int)((key1 & 1u) ^ 1u);
            if (!fallback && e0 == K_minopen) bex = 1;
        } else {
            // ---- exact slow path (INF tombstones present; rare) ------------
            ids_s[lane] = bid; dst_s[lane] = bds; exp_s[lane] = bex;
            if (lane < RNB) { ids_s[64 + lane] = nid; dst_s[64 + lane] = ndt; exp_s[64 + lane] = 0; }
            merge_slow(96, lane, ids_s, dst_s, exp_s, ids2, dst2, exp2);
            bid = ids_s[lane]; bds = dst_s[lane]; bex = exp_s[lane];
            u64 open = __ballot(bex == 0);
            int sel = open ? (int)(__ffsll((long long)open) - 1) : 0;
            int node = __shfl(bid, sel);
            if (lane == sel) bex = 1;
            if (!lastit) LOAD_IDX(node);
        }

        // ---- issue next storage loads, then hide the bookkeeping under them
        if (!lastit) {
            LOAD_ROWS();
            POSTMERGE_STATE();
        }
    }

    // ---- outputs: ids (as float, exact for id < 2^24) then dists
    if (lane < KTOP) {
        out[(size_t)b * KTOP + lane] = (float)bid;
        out[(size_t)B * KTOP + (size_t)b * KTOP + lane] = bds;
    }
}

extern "C" void kernel_launch(void* const* d_in, const int* in_sizes, int n_in,
                              void* d_out, int out_size, void* d_ws, size_t ws_size,
                              hipStream_t stream) {
    const float* query   = (const float*)d_in[0];
    const float* storage = (const float*)d_in[1];
    const int*   indices = (const int*)d_in[2];
    const int*   entry   = (const int*)d_in[3];
    int B = in_sizes[0] / DIM;
    float* out = (float*)d_out;
    nsw_search<<<B, 64, 0, stream>>>(query, storage, indices, entry, out, B);
}